// Round 16
// baseline (265.106 us; speedup 1.0000x reference)
//
#include <hip/hip_runtime.h>
#include <hip/hip_bf16.h>
#include <math.h>

typedef short bf16x8 __attribute__((ext_vector_type(8)));
typedef float f32x4 __attribute__((ext_vector_type(4)));
typedef short short4v __attribute__((ext_vector_type(4)));
typedef short short8v __attribute__((ext_vector_type(8)));

__device__ __forceinline__ short f2bf(float f) {
  unsigned u = __builtin_bit_cast(unsigned, f);
  unsigned r = (u + 0x7FFFu + ((u >> 16) & 1u)) >> 16;
  return (short)r;
}
__device__ __forceinline__ float bf2f(short s) {
  unsigned u = ((unsigned)(unsigned short)s) << 16;
  return __builtin_bit_cast(float, u);
}

typedef __attribute__((address_space(1))) const unsigned g_u32;
typedef __attribute__((address_space(3))) unsigned l_u32;
__device__ __forceinline__ void gload_lds16(const short* g, short* l) {
  __builtin_amdgcn_global_load_lds((g_u32*)g, (l_u32*)l, 16, 0, 0);
}

#define VMCNT(n) asm volatile("s_waitcnt vmcnt(" #n ")" ::: "memory")
#define LGKM(n) asm volatile("s_waitcnt lgkmcnt(" #n ")" ::: "memory")

// ---------------- merged casts (VERIFIED R14) ----------------
__global__ __launch_bounds__(256) void k_cast(const float* __restrict__ x,
                                              const float* __restrict__ Wq, const float* __restrict__ Wk,
                                              const float* __restrict__ Wv, const float* __restrict__ bq,
                                              const float* __restrict__ bk, const float* __restrict__ bv,
                                              short* __restrict__ xb, short* __restrict__ Wcat,
                                              float* __restrict__ biascat) {
  int bid = blockIdx.x;
  if (bid < 16384) {
    int tid = bid * 256 + threadIdx.x;
    int d4 = tid & 255;
    int sb = tid >> 8;
    int s = sb & 2047;
    int b = sb >> 11;
    float4 v = *((const float4*)(x + (((size_t)s * 8 + b) << 10)) + d4);
    short4v o;
    o.x = f2bf(v.x); o.y = f2bf(v.y); o.z = f2bf(v.z); o.w = f2bf(v.w);
    *((short4v*)(xb + (((size_t)b * 2048 + s) << 10)) + d4) = o;
  } else if (bid < 19456) {
    int tid = (bid - 16384) * 256 + threadIdx.x;
    int d4 = tid & 255;
    int n = tid >> 8;
    const float* src = (n < 1024) ? Wq : (n < 2048 ? Wk : Wv);
    int nl = n & 1023;
    float4 v = *((const float4*)(src + ((size_t)nl << 10)) + d4);
    short4v o;
    o.x = f2bf(v.x); o.y = f2bf(v.y); o.z = f2bf(v.z); o.w = f2bf(v.w);
    *((short4v*)(Wcat + ((size_t)n << 10)) + d4) = o;
  } else {
    int i = (bid - 19456) * 256 + threadIdx.x;
    if (i < 3072) biascat[i] = (i < 1024) ? bq[i] : (i < 2048 ? bk[i & 1023] : bv[i & 1023]);
  }
}

// ---------------- pipelined core: 256x128 tile, reads one phase AHEAD of MFMA ----------------
// 512 threads = 8 waves (4M x 2N); per-wave 64x64 -> acc[4][4] (16x16x32 MFMA).
// LDS: A-ring3 [256][32] + B-ring3 [128][32] = 72KB; 1 block/CU (launch_bounds(512,2)).
// Mechanism: phase c reads fr[c+1] (8 ds_read_b128, NOT consumed by this phase's MFMA),
// then MFMAs fr[c] (already in regs) -> LDS port services next-phase reads WHILE the
// matrix pipe runs, instead of strictly alternating (R10-R14's lockstep).
// Phase c: { rd fr[c+1]; stage pair(c+3); VMCNT(3); MFMA fr[c]; LGKM(0); barrier }
// *** R15 BUG FIX: a stage pair = 3 VMEM loads/thread (2A+1B). All drains are VMCNT(3)
// (R15's VMCNT(4) left the B-load of the oldest pair in flight across the barrier). ***
// Ledger (re-verified): entering phase c: fr[c] in regs, pair(c+1) landed, outstanding =
// pair(c+2) [3 loads]. stage pair(c+3) -> 6; VMCNT(3) drains pair(c+2) (read next phase).
// c+3==NC: VMCNT(0) drains pair(NC-1). c+3>NC: nothing outstanding.
// Slot safety: slot c%3's ds_reads complete at phase c-1's explicit LGKM(0) BEFORE the
// barrier (auto-waits are at use, which may be post-barrier -> LGKM(0) is load-bearing);
// pair(c+3) (same slot) issues only after that barrier. In-flight writes at phase c are
// pair(c+2)->slot (c+2)%3 and pair(c+3)->slot c%3; reads are slot (c+1)%3 -> disjoint.
// Prologue: stage 0,1; VMCNT(3); bar; rd fr[0]; stage 2; VMCNT(3); LGKM(0); bar.
// NC must be even (all callers: 32 or 8*(mt+1)).
template <int LDA, int LDB>
__device__ __forceinline__ void gemm128p_core(const short* __restrict__ Ag, const short* __restrict__ Bg,
                                              int NC, short* __restrict__ lds, f32x4 (&acc)[4][4], int tid) {
  const int lane = tid & 63;
  const int wid = tid >> 6;
  const int wm = wid >> 1, wn = wid & 1;
  const int r15 = lane & 15;
  const int g = lane >> 4;
  const int co = ((g ^ ((r15 >> 1) & 3)) << 3);
  short* As = lds;                 // 3 x 8192 shorts
  short* Bs = lds + 3 * 8192;      // 3 x 4096 shorts

  const int abase = (wm * 64 + r15) * 32 + co;
  const int bbase = (wn * 64 + r15) * 32 + co;

  auto stage_pair = [&](int c) {   // A: 2 loads/thread; B: 1 load/thread => 3 VMEM total
    short* Ap = As + (c % 3) * 8192;
    short* Bp = Bs + (c % 3) * 4096;
    int kb = c << 5;
#pragma unroll
    for (int i = 0; i < 2; ++i) {
      int ch = i * 512 + tid;
      int r = ch >> 2, s = ch & 3;
      gload_lds16(Ag + (size_t)r * LDA + kb + ((s ^ ((r >> 1) & 3)) << 3), Ap + ch * 8);
    }
    {
      int r = tid >> 2, s = tid & 3;
      gload_lds16(Bg + (size_t)r * LDB + kb + ((s ^ ((r >> 1) & 3)) << 3), Bp + tid * 8);
    }
  };

  bf16x8 aA[4], bA[4], aB[4], bB[4];
  auto rd = [&](bf16x8 (&a4)[4], bf16x8 (&br)[4], int c) {
    const short* pa = As + (c % 3) * 8192 + abase;
    const short* pb = Bs + (c % 3) * 4096 + bbase;
#pragma unroll
    for (int mf = 0; mf < 4; ++mf) a4[mf] = *(const bf16x8*)(pa + mf * 512);
#pragma unroll
    for (int nf = 0; nf < 4; ++nf) br[nf] = *(const bf16x8*)(pb + nf * 512);
  };
  auto mm = [&](bf16x8 (&a4)[4], bf16x8 (&br)[4]) {
    __builtin_amdgcn_s_setprio(1);
#pragma unroll
    for (int mf = 0; mf < 4; ++mf)
#pragma unroll
      for (int nf = 0; nf < 4; ++nf)
        acc[mf][nf] = __builtin_amdgcn_mfma_f32_16x16x32_bf16(a4[mf], br[nf], acc[mf][nf], 0, 0, 0);
    __builtin_amdgcn_s_setprio(0);
  };
  auto waits = [&](int c) {
    if (c + 3 < NC) {
      stage_pair(c + 3);
      VMCNT(3);            // drains pair(c+2), keeps pair(c+3)
    } else if (c + 3 == NC) {
      VMCNT(0);            // drains pair(NC-1), the last one
    }                      // else: nothing outstanding
  };

  // prologue
  stage_pair(0);
  stage_pair(1);
  VMCNT(3);                // drain pair(0), keep pair(1)
  __builtin_amdgcn_s_barrier();
  rd(aA, bA, 0);
  stage_pair(2);
  VMCNT(3);                // drain pair(1), keep pair(2)
  LGKM(0);
  __builtin_amdgcn_s_barrier();

  int c = 0;
  for (; c + 3 < NC; c += 2) {
    // phase c (even): current = A-set, prefetch -> B-set
    rd(aB, bB, c + 1);
    waits(c);
    mm(aA, bA);
    LGKM(0);
    __builtin_amdgcn_s_barrier();
    // phase c+1 (odd): current = B-set, prefetch -> A-set
    rd(aA, bA, c + 2);
    waits(c + 1);
    mm(aB, bB);
    LGKM(0);
    __builtin_amdgcn_s_barrier();
  }
  // c == NC-2 (NC even). Phase NC-2: prefetch last chunk; nothing outstanding.
  rd(aB, bB, NC - 1);
  mm(aA, bA);
  LGKM(0);
  __builtin_amdgcn_s_barrier();
  // phase NC-1: final MFMA only
  mm(aB, bB);
}

// ---------------- QKV projection: 256x128 tiles, 1536 blocks, pipelined core ----------------
// Q, K stored (B,S,A) bf16; V stored TRANSPOSED as Vt (B,A,S) bf16.
__global__ __launch_bounds__(512, 2) void k_proj(const short* __restrict__ Xb, const short* __restrict__ Wc,
                                                 const float* __restrict__ biascat,
                                                 short* __restrict__ Q, short* __restrict__ K, short* __restrict__ Vt) {
  __shared__ __align__(16) short lds[36864];   // 72 KiB
  int tid = threadIdx.x;
  int wg = blockIdx.x;                         // 1536 blocks
  int swz = (wg & 7) * 192 + (wg >> 3);        // bijective XCD swizzle
  int mt = swz / 24, nt = swz % 24;
  int m0 = mt << 8, n0 = nt << 7;
  f32x4 acc[4][4] = {};
  gemm128p_core<1024, 1024>(Xb + (size_t)m0 * 1024, Wc + (size_t)n0 * 1024, 32, lds, acc, tid);
  int lane = tid & 63, wid = tid >> 6;
  int wm = wid >> 1, wn = wid & 1;
  int r15 = lane & 15, g = lane >> 4;
  int which = n0 >> 10;
  int nbase = n0 & 1023;
  if (which == 2) {
#pragma unroll
    for (int ni = 0; ni < 4; ++ni) {
      int cth = wn * 64 + ni * 16 + r15;
      int a = nbase + cth;
      float bv = biascat[n0 + cth];
#pragma unroll
      for (int mi = 0; mi < 4; ++mi) {
        int r = m0 + wm * 64 + mi * 16 + g * 4;
        int b = r >> 11, s = r & 2047;
        short4v o;
#pragma unroll
        for (int j = 0; j < 4; ++j) o[j] = f2bf(acc[mi][ni][j] + bv);
        *(short4v*)(Vt + ((size_t)b << 21) + ((size_t)a << 11) + s) = o;
      }
    }
  } else {
    short* outb = (which == 0) ? Q : K;
#pragma unroll
    for (int ni = 0; ni < 4; ++ni) {
      int cth = wn * 64 + ni * 16 + r15;
      float bv = biascat[n0 + cth];
#pragma unroll
      for (int mi = 0; mi < 4; ++mi)
#pragma unroll
        for (int j = 0; j < 4; ++j) {
          int r = m0 + wm * 64 + mi * 16 + g * 4 + j;
          outb[((size_t)r << 10) + nbase + cth] = f2bf(acc[mi][ni][j] + bv);
        }
    }
  }
}

// ---------------- QK^T: causal 256x128 tiles, pipelined core ----------------
__global__ __launch_bounds__(512, 2) void k_qk(const short* __restrict__ Q, const short* __restrict__ K,
                                               short* __restrict__ Sc) {
  __shared__ __align__(16) short lds[36864];
  int f = blockIdx.x;                        // 0..575
  int b = f & 7;                             // batch == XCD
  int idx = f >> 3;                          // 0..71
  int mt = (int)((sqrtf(4.f * idx + 1.f) - 1.f) * 0.5f);
  while ((mt + 1) * (mt + 2) <= idx) ++mt;
  while (mt * (mt + 1) > idx) --mt;
  int nt = idx - mt * (mt + 1);
  int tid = threadIdx.x;
  int m0 = mt << 8, n0 = nt << 7;
  const short* Qb = Q + ((size_t)b << 21);
  const short* Kb = K + ((size_t)b << 21);
  f32x4 acc[4][4] = {};
  gemm128p_core<1024, 1024>(Qb + (size_t)m0 * 1024, Kb + (size_t)n0 * 1024, 32, lds, acc, tid);
  short* Sb = Sc + ((size_t)b << 22);
  int lane = tid & 63, wid = tid >> 6;
  int wm = wid >> 1, wn = wid & 1;
  int r15 = lane & 15, g = lane >> 4;
#pragma unroll
  for (int mi = 0; mi < 4; ++mi)
#pragma unroll
    for (int ni = 0; ni < 4; ++ni)
#pragma unroll
      for (int j = 0; j < 4; ++j) {
        int r = m0 + wm * 64 + mi * 16 + g * 4 + j;
        int c = n0 + wn * 64 + ni * 16 + r15;
        Sb[((size_t)r << 11) + c] = f2bf(acc[mi][ni][j] * 0.03125f);
      }
}

// ---------------- row softmax: one WAVE per row (VERIFIED R12) ----------------
__global__ __launch_bounds__(256) void k_softmax(short* __restrict__ Sc) {
  int row = blockIdx.x * 4 + (threadIdx.x >> 6);
  int lane = threadIdx.x & 63;
  int b = row >> 11, q = row & 2047;
  short* Pr = Sc + ((size_t)b << 22) + ((size_t)q << 11);
  int T = ((q >> 8) + 1) << 8;
  float v[4][8];
  float mx = -__builtin_inff();
#pragma unroll
  for (int it = 0; it < 4; ++it) {
    int k0 = it * 512 + lane * 8;
    if (k0 < T) {
      short8v raw = *(const short8v*)(Pr + k0);
#pragma unroll
      for (int j = 0; j < 8; ++j) {
        float xv = (k0 + j <= q) ? bf2f(raw[j]) : -__builtin_inff();
        v[it][j] = xv;
        mx = fmaxf(mx, xv);
      }
    }
  }
  for (int off = 1; off < 64; off <<= 1) mx = fmaxf(mx, __shfl_xor(mx, off, 64));
  float sum = 0.f;
#pragma unroll
  for (int it = 0; it < 4; ++it) {
    int k0 = it * 512 + lane * 8;
    if (k0 < T) {
#pragma unroll
      for (int j = 0; j < 8; ++j) {
        float e = exp2f((v[it][j] - mx) * 1.4426950408889634f);
        v[it][j] = e;
        sum += e;
      }
    }
  }
  for (int off = 1; off < 64; off <<= 1) sum += __shfl_xor(sum, off, 64);
  float inv = 1.f / sum;
#pragma unroll
  for (int it = 0; it < 4; ++it) {
    int k0 = it * 512 + lane * 8;
    if (k0 < T) {
      short8v o;
#pragma unroll
      for (int j = 0; j < 8; ++j) o[j] = (k0 + j <= q) ? f2bf(v[it][j] * inv) : (short)0;
      *(short8v*)(Pr + k0) = o;
    }
  }
}

// ---------------- PV: pipelined core, complementary-mt pairing ----------------
__global__ __launch_bounds__(512, 2) void k_pv(const short* __restrict__ P, const short* __restrict__ Vt,
                                               float* __restrict__ out) {
  __shared__ __align__(16) short lds[36864];
  int f = blockIdx.x;                        // 0..511
  int b = f & 7;                             // batch == XCD
  int idx = f >> 3;                          // 0..63
  int half = idx >> 5, j = idx & 31;
  int mt = half ? (7 - (j >> 2)) : (j >> 2);
  int nt = half ? (4 + (j & 3)) : (j & 3);
  int tid = threadIdx.x;
  int m0 = mt << 8, n0 = nt << 7;
  int NC = 8 * (mt + 1);
  const short* Pb = P + ((size_t)b << 22);
  const short* Vtb = Vt + ((size_t)b << 21);
  f32x4 acc[4][4] = {};
  gemm128p_core<2048, 2048>(Pb + (size_t)m0 * 2048, Vtb + (size_t)n0 * 2048, NC, lds, acc, tid);
  int lane = tid & 63, wid = tid >> 6;
  int wm = wid >> 1, wn = wid & 1;
  int r15 = lane & 15, g = lane >> 4;
#pragma unroll
  for (int mi = 0; mi < 4; ++mi)
#pragma unroll
    for (int ni = 0; ni < 4; ++ni)
#pragma unroll
      for (int j2 = 0; j2 < 4; ++j2) {
        int r = m0 + wm * 64 + mi * 16 + g * 4 + j2;   // q
        int c = n0 + wn * 64 + ni * 16 + r15;          // a
        out[((size_t)r << 13) + ((size_t)b << 10) + c] = acc[mi][ni][j2];
      }
}

extern "C" void kernel_launch(void* const* d_in, const int* in_sizes, int n_in,
                              void* d_out, int out_size, void* d_ws, size_t ws_size,
                              hipStream_t stream) {
  const float* x  = (const float*)d_in[0];
  const float* Wq = (const float*)d_in[1];
  const float* bq = (const float*)d_in[2];
  const float* Wk = (const float*)d_in[3];
  const float* bk = (const float*)d_in[4];
  const float* Wv = (const float*)d_in[5];
  const float* bv = (const float*)d_in[6];
  float* out = (float*)d_out;
  char* ws = (char*)d_ws;

  short* xb   = (short*)(ws);                    // 33,554,432 B
  short* Wcat = (short*)(ws + 33554432);         //  6,291,456 B
  float* bias = (float*)(ws + 39845888);         //     12,288 B
  short* Q    = (short*)(ws + 39858176);         // 33,554,432 B
  short* K    = (short*)(ws + 73412608);         // 33,554,432 B
  short* Vt   = (short*)(ws + 106967040);        // 33,554,432 B (written transposed by k_proj)
  short* Sc   = (short*)(ws + 140521472);        // 67,108,864 B

  k_cast<<<19468, 256, 0, stream>>>(x, Wq, Wk, Wv, bq, bk, bv, xb, Wcat, bias);
  k_proj<<<1536, 512, 0, stream>>>(xb, Wcat, bias, Q, K, Vt);
  k_qk<<<576, 512, 0, stream>>>(Q, K, Sc);
  k_softmax<<<4096, 256, 0, stream>>>(Sc);
  k_pv<<<512, 512, 0, stream>>>(Sc, Vt, out);
}

// Round 17
// 249.916 us; speedup vs baseline: 1.0608x; 1.0608x over previous
//
#include <hip/hip_runtime.h>
#include <hip/hip_bf16.h>
#include <math.h>

typedef short bf16x8 __attribute__((ext_vector_type(8)));
typedef float f32x4 __attribute__((ext_vector_type(4)));
typedef short short4v __attribute__((ext_vector_type(4)));
typedef short short8v __attribute__((ext_vector_type(8)));

__device__ __forceinline__ short f2bf(float f) {
  unsigned u = __builtin_bit_cast(unsigned, f);
  unsigned r = (u + 0x7FFFu + ((u >> 16) & 1u)) >> 16;
  return (short)r;
}
__device__ __forceinline__ float bf2f(short s) {
  unsigned u = ((unsigned)(unsigned short)s) << 16;
  return __builtin_bit_cast(float, u);
}

typedef __attribute__((address_space(1))) const unsigned g_u32;
typedef __attribute__((address_space(3))) unsigned l_u32;
__device__ __forceinline__ void gload_lds16(const short* g, short* l) {
  __builtin_amdgcn_global_load_lds((g_u32*)g, (l_u32*)l, 16, 0, 0);
}

#define VMCNT(n) asm volatile("s_waitcnt vmcnt(" #n ")" ::: "memory")

// ---------------- casts (VERIFIED R12 config) ----------------

__global__ __launch_bounds__(256) void k_cast_x(const float* __restrict__ x, short* __restrict__ xb) {
  int tid = blockIdx.x * 256 + threadIdx.x;
  int d4 = tid & 255;
  int sb = tid >> 8;
  int s = sb & 2047;
  int b = sb >> 11;
  float4 v = *((const float4*)(x + (((size_t)s * 8 + b) << 10)) + d4);
  short4v o;
  o.x = f2bf(v.x); o.y = f2bf(v.y); o.z = f2bf(v.z); o.w = f2bf(v.w);
  *((short4v*)(xb + (((size_t)b * 2048 + s) << 10)) + d4) = o;
}

__global__ __launch_bounds__(256) void k_cast_w(const float* __restrict__ Wq, const float* __restrict__ Wk,
                                                const float* __restrict__ Wv, short* __restrict__ Wcat) {
  int tid = blockIdx.x * 256 + threadIdx.x;
  int d4 = tid & 255;
  int n = tid >> 8;
  const float* src = (n < 1024) ? Wq : (n < 2048 ? Wk : Wv);
  int nl = n & 1023;
  float4 v = *((const float4*)(src + ((size_t)nl << 10)) + d4);
  short4v o;
  o.x = f2bf(v.x); o.y = f2bf(v.y); o.z = f2bf(v.z); o.w = f2bf(v.w);
  *((short4v*)(Wcat + ((size_t)n << 10)) + d4) = o;
}

__global__ __launch_bounds__(256) void k_cast_bias(const float* __restrict__ bq, const float* __restrict__ bk,
                                                   const float* __restrict__ bv, float* __restrict__ biascat) {
  int i = blockIdx.x * 256 + threadIdx.x;
  if (i < 3072) biascat[i] = (i < 1024) ? bq[i] : (i < 2048 ? bk[i & 1023] : bv[i & 1023]);
}

// ---------------- proj core (VERIFIED R12, 121.5us): 256x256 tile, operand-hold ----------------
// 512 threads = 8 waves (2M x 4N); per-wave 128x64 -> acc[8][4] (16x16x32 MFMA).
// LDS: per operand 4 K-half slots [256 rows][32 k] bf16 (2buf x 2kk) = 64KB; A+B = 128KB.
// Slot swizzle slot^=(row>>1)&3 (0 conflicts, PMC-verified). Per K-tile(64): 4 phases:
//  ph1: rdA[mh0,kk0]+rdB[kk0]; stageA(t+1,k0); bar; MFMA acc[0-3]; bar
//  ph2: rdA[mh1,kk0] [B held]; stageB(t+1,k0); VMCNT(4); bar; MFMA acc[4-7]; bar
//  ph3: rdA[mh0,kk1]+rdB[kk1]; stageA(t+1,k1); bar; MFMA acc[0-3]; bar
//  ph4: rdA[mh1,kk1] [B held]; stageB(t+1,k1); VMCNT(4); bar; MFMA acc[4-7]; bar
// Ledger: steady invariant entering ph1(t): outstanding = {A(t,k1),B(t,k1)} (4 loads).
// VMCNT(4)@ph2 drains them (needed ph3); VMCNT(4)@ph4 drains t+1's k0 pair (needed ph1(t+1)).
// Prologue A(0,k0),B(0,k0),A(0,k1),B(0,k1); VMCNT(4). Last tile: VMCNT(0)@ph2.
template <int LDA, int LDB>
__device__ __forceinline__ void gemm256h_core(const short* __restrict__ Ag, const short* __restrict__ Bg,
                                              int NT, short* __restrict__ lds, f32x4 (&acc)[8][4], int tid) {
  const int lane = tid & 63;
  const int wid = tid >> 6;
  const int wm = wid >> 2, wn = wid & 3;
  const int r15 = lane & 15;
  const int g = lane >> 4;
  const int co = ((g ^ ((r15 >> 1) & 3)) << 3);
  short* As = lds;             // 4 slots x 8192 shorts
  short* Bs = lds + 32768;

  auto stageA = [&](int t, int kk) {
    short* Lp = As + (((t & 1) * 2 + kk) << 13);
    int kb = (t << 6) + (kk << 5);
#pragma unroll
    for (int i = 0; i < 2; ++i) {
      int ch = i * 512 + tid;
      int r = ch >> 2, s = ch & 3;
      gload_lds16(Ag + (size_t)r * LDA + kb + ((s ^ ((r >> 1) & 3)) << 3), Lp + ch * 8);
    }
  };
  auto stageB = [&](int t, int kk) {
    short* Lp = Bs + (((t & 1) * 2 + kk) << 13);
    int kb = (t << 6) + (kk << 5);
#pragma unroll
    for (int i = 0; i < 2; ++i) {
      int ch = i * 512 + tid;
      int r = ch >> 2, s = ch & 3;
      gload_lds16(Bg + (size_t)r * LDB + kb + ((s ^ ((r >> 1) & 3)) << 3), Lp + ch * 8);
    }
  };

  bf16x8 a4[4], br[4];
  auto rdA = [&](int t, int kk, int mh) {
    const short* p = As + (((t & 1) * 2 + kk) << 13) + (wm * 128 + mh * 64 + r15) * 32 + co;
#pragma unroll
    for (int mf = 0; mf < 4; ++mf) a4[mf] = *(const bf16x8*)(p + mf * 512);
  };
  auto rdB = [&](int t, int kk) {
    const short* p = Bs + (((t & 1) * 2 + kk) << 13) + (wn * 64 + r15) * 32 + co;
#pragma unroll
    for (int nf = 0; nf < 4; ++nf) br[nf] = *(const bf16x8*)(p + nf * 512);
  };
  auto mm = [&](int mh) {
    __builtin_amdgcn_s_setprio(1);
#pragma unroll
    for (int mf = 0; mf < 4; ++mf)
#pragma unroll
      for (int nf = 0; nf < 4; ++nf)
        acc[mh * 4 + mf][nf] =
            __builtin_amdgcn_mfma_f32_16x16x32_bf16(a4[mf], br[nf], acc[mh * 4 + mf][nf], 0, 0, 0);
    __builtin_amdgcn_s_setprio(0);
  };

  // prologue
  stageA(0, 0); stageB(0, 0); stageA(0, 1); stageB(0, 1);
  VMCNT(4);
  __builtin_amdgcn_s_barrier();

  for (int t = 0; t < NT; ++t) {
    const bool more = (t + 1 < NT);
    // ph1
    rdA(t, 0, 0); rdB(t, 0);
    if (more) stageA(t + 1, 0);
    __builtin_amdgcn_s_barrier();
    mm(0);
    __builtin_amdgcn_s_barrier();
    // ph2
    rdA(t, 0, 1);
    if (more) { stageB(t + 1, 0); VMCNT(4); } else { VMCNT(0); }
    __builtin_amdgcn_s_barrier();
    mm(1);
    __builtin_amdgcn_s_barrier();
    // ph3
    rdA(t, 1, 0); rdB(t, 1);
    if (more) stageA(t + 1, 1);
    __builtin_amdgcn_s_barrier();
    mm(0);
    __builtin_amdgcn_s_barrier();
    // ph4
    rdA(t, 1, 1);
    if (more) { stageB(t + 1, 1); VMCNT(4); }
    __builtin_amdgcn_s_barrier();
    mm(1);
    __builtin_amdgcn_s_barrier();
  }
}

// ---------------- co-residency core (VERIFIED R10/R11/R12) ----------------
template <int LDA, int LDB>
__device__ __forceinline__ void gemm128n_core(const short* __restrict__ Ag, const short* __restrict__ Bg,
                                              int NC, short* __restrict__ lds, f32x4 (&acc)[4][4], int tid) {
  const int lane = tid & 63;
  const int wid = tid >> 6;
  const int wm = wid >> 1, wn = wid & 1;
  const int r15 = lane & 15;
  const int g = lane >> 4;
  const int co = ((g ^ ((r15 >> 1) & 3)) << 3);
  short* As = lds;                 // 3 x 8192 shorts
  short* Bs = lds + 3 * 8192;      // 3 x 4096 shorts

  const int abase = (wm * 64 + r15) * 32 + co;
  const int bbase = (wn * 64 + r15) * 32 + co;

  auto stage_pair = [&](int c) {
    short* Ap = As + (c % 3) * 8192;
    short* Bp = Bs + (c % 3) * 4096;
    int kb = c << 5;
#pragma unroll
    for (int i = 0; i < 2; ++i) {
      int ch = i * 512 + tid;
      int r = ch >> 2, s = ch & 3;
      gload_lds16(Ag + (size_t)r * LDA + kb + ((s ^ ((r >> 1) & 3)) << 3), Ap + ch * 8);
    }
    {
      int r = tid >> 2, s = tid & 3;
      gload_lds16(Bg + (size_t)r * LDB + kb + ((s ^ ((r >> 1) & 3)) << 3), Bp + tid * 8);
    }
  };

  auto phase = [&](int c, bool stage, bool last) {
    bf16x8 a4[4], br[4];
    const short* pa = As + (c % 3) * 8192 + abase;
    const short* pb = Bs + (c % 3) * 4096 + bbase;
#pragma unroll
    for (int mf = 0; mf < 4; ++mf) a4[mf] = *(const bf16x8*)(pa + mf * 512);
#pragma unroll
    for (int nf = 0; nf < 4; ++nf) br[nf] = *(const bf16x8*)(pb + nf * 512);
    if (stage) {
      stage_pair(c + 2);
      VMCNT(3);
    } else if (!last) {
      VMCNT(0);
    }
    __builtin_amdgcn_s_barrier();
    asm volatile("s_waitcnt lgkmcnt(0)" ::: "memory");
    __builtin_amdgcn_sched_barrier(0);
    __builtin_amdgcn_s_setprio(1);
#pragma unroll
    for (int mf = 0; mf < 4; ++mf)
#pragma unroll
      for (int nf = 0; nf < 4; ++nf)
        acc[mf][nf] = __builtin_amdgcn_mfma_f32_16x16x32_bf16(a4[mf], br[nf], acc[mf][nf], 0, 0, 0);
    __builtin_amdgcn_s_setprio(0);
    __builtin_amdgcn_s_barrier();
  };

  stage_pair(0);
  stage_pair(1);
  VMCNT(3);
  __builtin_amdgcn_s_barrier();

  for (int c = 0; c < NC - 2; ++c) phase(c, true, false);
  phase(NC - 2, false, false);
  phase(NC - 1, false, true);
}

// ---------------- QKV projection (VERIFIED R12): gemm256h, 768 blocks ----------------
__global__ __launch_bounds__(512, 1) void k_proj(const short* __restrict__ Xb, const short* __restrict__ Wc,
                                                 const float* __restrict__ biascat,
                                                 short* __restrict__ Q, short* __restrict__ K, short* __restrict__ Vt) {
  __shared__ __align__(16) short lds[65536];
  int tid = threadIdx.x;
  int wg = blockIdx.x;                       // 768 blocks
  int swz = (wg & 7) * 96 + (wg >> 3);       // bijective XCD swizzle
  int mt = swz / 12, nt = swz % 12;
  int m0 = mt << 8, n0 = nt << 8;
  f32x4 acc[8][4] = {};
  gemm256h_core<1024, 1024>(Xb + (size_t)m0 * 1024, Wc + (size_t)n0 * 1024, 16, lds, acc, tid);
  int lane = tid & 63, wid = tid >> 6;
  int wm = wid >> 2, wn = wid & 3;
  int r15 = lane & 15, g = lane >> 4;
  int which = n0 >> 10;
  int nbase = n0 & 1023;
  if (which == 2) {
#pragma unroll
    for (int ni = 0; ni < 4; ++ni) {
      int cth = wn * 64 + ni * 16 + r15;
      int a = nbase + cth;
      float bv = biascat[n0 + cth];
#pragma unroll
      for (int mi = 0; mi < 8; ++mi) {
        int r = m0 + wm * 128 + (mi >> 2) * 64 + (mi & 3) * 16 + g * 4;
        int b = r >> 11, s = r & 2047;
        short4v o;
#pragma unroll
        for (int j = 0; j < 4; ++j) o[j] = f2bf(acc[mi][ni][j] + bv);
        *(short4v*)(Vt + ((size_t)b << 21) + ((size_t)a << 11) + s) = o;
      }
    }
  } else {
    short* outb = (which == 0) ? Q : K;
#pragma unroll
    for (int ni = 0; ni < 4; ++ni) {
      int cth = wn * 64 + ni * 16 + r15;
      float bv = biascat[n0 + cth];
#pragma unroll
      for (int mi = 0; mi < 8; ++mi)
#pragma unroll
        for (int j = 0; j < 4; ++j) {
          int r = m0 + wm * 128 + (mi >> 2) * 64 + (mi & 3) * 16 + g * 4 + j;
          outb[((size_t)r << 10) + nbase + cth] = f2bf(acc[mi][ni][j] + bv);
        }
    }
  }
}

// ---------------- QK^T (VERIFIED R11/R12): causal 256x128 tiles, co-resident core ----------------
__global__ __launch_bounds__(512, 4) void k_qk(const short* __restrict__ Q, const short* __restrict__ K,
                                               short* __restrict__ Sc) {
  __shared__ __align__(16) short lds[36864];
  int f = blockIdx.x;                        // 0..575
  int b = f & 7;                             // batch == XCD
  int idx = f >> 3;                          // 0..71
  int mt = (int)((sqrtf(4.f * idx + 1.f) - 1.f) * 0.5f);
  while ((mt + 1) * (mt + 2) <= idx) ++mt;
  while (mt * (mt + 1) > idx) --mt;
  int nt = idx - mt * (mt + 1);
  int tid = threadIdx.x;
  int m0 = mt << 8, n0 = nt << 7;
  const short* Qb = Q + ((size_t)b << 21);
  const short* Kb = K + ((size_t)b << 21);
  f32x4 acc[4][4] = {};
  gemm128n_core<1024, 1024>(Qb + (size_t)m0 * 1024, Kb + (size_t)n0 * 1024, 32, lds, acc, tid);
  short* Sb = Sc + ((size_t)b << 22);
  int lane = tid & 63, wid = tid >> 6;
  int wm = wid >> 1, wn = wid & 1;
  int r15 = lane & 15, g = lane >> 4;
#pragma unroll
  for (int mi = 0; mi < 4; ++mi)
#pragma unroll
    for (int ni = 0; ni < 4; ++ni)
#pragma unroll
      for (int j = 0; j < 4; ++j) {
        int r = m0 + wm * 64 + mi * 16 + g * 4 + j;
        int c = n0 + wn * 64 + ni * 16 + r15;
        Sb[((size_t)r << 11) + c] = f2bf(acc[mi][ni][j] * 0.03125f);
      }
}

// ---------------- row softmax: one WAVE per row (VERIFIED R12) ----------------
__global__ __launch_bounds__(256) void k_softmax(short* __restrict__ Sc) {
  int row = blockIdx.x * 4 + (threadIdx.x >> 6);
  int lane = threadIdx.x & 63;
  int b = row >> 11, q = row & 2047;
  short* Pr = Sc + ((size_t)b << 22) + ((size_t)q << 11);
  int T = ((q >> 8) + 1) << 8;
  float v[4][8];
  float mx = -__builtin_inff();
#pragma unroll
  for (int it = 0; it < 4; ++it) {
    int k0 = it * 512 + lane * 8;
    if (k0 < T) {
      short8v raw = *(const short8v*)(Pr + k0);
#pragma unroll
      for (int j = 0; j < 8; ++j) {
        float xv = (k0 + j <= q) ? bf2f(raw[j]) : -__builtin_inff();
        v[it][j] = xv;
        mx = fmaxf(mx, xv);
      }
    }
  }
  for (int off = 1; off < 64; off <<= 1) mx = fmaxf(mx, __shfl_xor(mx, off, 64));
  float sum = 0.f;
#pragma unroll
  for (int it = 0; it < 4; ++it) {
    int k0 = it * 512 + lane * 8;
    if (k0 < T) {
#pragma unroll
      for (int j = 0; j < 8; ++j) {
        float e = exp2f((v[it][j] - mx) * 1.4426950408889634f);
        v[it][j] = e;
        sum += e;
      }
    }
  }
  for (int off = 1; off < 64; off <<= 1) sum += __shfl_xor(sum, off, 64);
  float inv = 1.f / sum;
#pragma unroll
  for (int it = 0; it < 4; ++it) {
    int k0 = it * 512 + lane * 8;
    if (k0 < T) {
      short8v o;
#pragma unroll
      for (int j = 0; j < 8; ++j) o[j] = (k0 + j <= q) ? f2bf(v[it][j] * inv) : (short)0;
      *(short8v*)(Pr + k0) = o;
    }
  }
}

// ---------------- PV (VERIFIED R11/R12): co-resident core, complementary-mt pairing ----------------
__global__ __launch_bounds__(512, 4) void k_pv(const short* __restrict__ P, const short* __restrict__ Vt,
                                               float* __restrict__ out) {
  __shared__ __align__(16) short lds[36864];
  int f = blockIdx.x;                        // 0..511
  int b = f & 7;                             // batch == XCD
  int idx = f >> 3;                          // 0..63
  int half = idx >> 5, j = idx & 31;
  int mt = half ? (7 - (j >> 2)) : (j >> 2);
  int nt = half ? (4 + (j & 3)) : (j & 3);
  int tid = threadIdx.x;
  int m0 = mt << 8, n0 = nt << 7;
  int NC = 8 * (mt + 1);
  const short* Pb = P + ((size_t)b << 22);
  const short* Vtb = Vt + ((size_t)b << 21);
  f32x4 acc[4][4] = {};
  gemm128n_core<2048, 2048>(Pb + (size_t)m0 * 2048, Vtb + (size_t)n0 * 2048, NC, lds, acc, tid);
  int lane = tid & 63, wid = tid >> 6;
  int wm = wid >> 1, wn = wid & 1;
  int r15 = lane & 15, g = lane >> 4;
#pragma unroll
  for (int mi = 0; mi < 4; ++mi)
#pragma unroll
    for (int ni = 0; ni < 4; ++ni)
#pragma unroll
      for (int j2 = 0; j2 < 4; ++j2) {
        int r = m0 + wm * 64 + mi * 16 + g * 4 + j2;   // q
        int c = n0 + wn * 64 + ni * 16 + r15;          // a
        out[((size_t)r << 13) + ((size_t)b << 10) + c] = acc[mi][ni][j2];
      }
}

extern "C" void kernel_launch(void* const* d_in, const int* in_sizes, int n_in,
                              void* d_out, int out_size, void* d_ws, size_t ws_size,
                              hipStream_t stream) {
  const float* x  = (const float*)d_in[0];
  const float* Wq = (const float*)d_in[1];
  const float* bq = (const float*)d_in[2];
  const float* Wk = (const float*)d_in[3];
  const float* bk = (const float*)d_in[4];
  const float* Wv = (const float*)d_in[5];
  const float* bv = (const float*)d_in[6];
  float* out = (float*)d_out;
  char* ws = (char*)d_ws;

  short* xb   = (short*)(ws);                    // 33,554,432 B
  short* Wcat = (short*)(ws + 33554432);         //  6,291,456 B
  float* bias = (float*)(ws + 39845888);         //     12,288 B
  short* Q    = (short*)(ws + 39858176);         // 33,554,432 B
  short* K    = (short*)(ws + 73412608);         // 33,554,432 B
  short* Vt   = (short*)(ws + 106967040);        // 33,554,432 B (written transposed by k_proj)
  short* Sc   = (short*)(ws + 140521472);        // 67,108,864 B

  k_cast_x<<<16384, 256, 0, stream>>>(x, xb);
  k_cast_w<<<3072, 256, 0, stream>>>(Wq, Wk, Wv, Wcat);
  k_cast_bias<<<12, 256, 0, stream>>>(bq, bk, bv, bias);
  k_proj<<<768, 512, 0, stream>>>(xb, Wcat, bias, Q, K, Vt);
  k_qk<<<576, 512, 0, stream>>>(Q, K, Sc);
  k_softmax<<<4096, 256, 0, stream>>>(Sc);
  k_pv<<<512, 512, 0, stream>>>(Sc, Vt, out);
}